// Round 4
// baseline (653.632 us; speedup 1.0000x reference)
//
#include <hip/hip_runtime.h>
#include <hip/hip_bf16.h>

#define NN 50000
#define NE 800000
#define H 128
#define DE 16
#define BN_EPS 1e-5f

typedef float v2f __attribute__((ext_vector_type(2)));
typedef float v4f __attribute__((ext_vector_type(4)));

__device__ __forceinline__ unsigned int packbf2(float a, float b) {
    __hip_bfloat162 h = __float22bfloat162_rn(make_float2(a, b));
    return *(unsigned int*)&h;
}
__device__ __forceinline__ v2f unpackbf2(unsigned int u) {
    v2f r;
    r.x = __uint_as_float(u << 16);
    r.y = __uint_as_float(u & 0xffff0000u);
    return r;
}

// ---------------- CSR build ----------------
__global__ void hist_k(const int* __restrict__ dst, int* __restrict__ counts) {
    int e = blockIdx.x * 256 + threadIdx.x;
    if (e < NE) atomicAdd(&counts[dst[e]], 1);
}

__global__ void dinv_k(const int* __restrict__ counts, float* __restrict__ dinv) {
    int i = blockIdx.x * 256 + threadIdx.x;
    if (i < NN) dinv[i] = rsqrtf((float)counts[i] + 1.0f);
}

__global__ __launch_bounds__(1024) void scan_k(const int* __restrict__ counts,
                                               int* __restrict__ offsets,
                                               int* __restrict__ cursor) {
    __shared__ int part[1024];
    int t = threadIdx.x;
    const int CH = (NN + 1023) / 1024;  // 49
    int lo = t * CH, hi = min(lo + CH, NN);
    int s = 0;
    for (int i = lo; i < hi; i++) s += counts[i];
    part[t] = s;
    __syncthreads();
    for (int off = 1; off < 1024; off <<= 1) {
        int v = 0;
        if (t >= off) v = part[t - off];
        __syncthreads();
        part[t] += v;
        __syncthreads();
    }
    int run = part[t] - s;  // exclusive prefix
    for (int i = lo; i < hi; i++) {
        offsets[i] = run;
        cursor[i]  = run;
        run += counts[i];
    }
}

// CSR payload: SoA (src id, original edge id)
__global__ void fill_k(const int* __restrict__ src, const int* __restrict__ dst,
                       int* __restrict__ cursor, int* __restrict__ srcs,
                       int* __restrict__ eids) {
    int e = blockIdx.x * 256 + threadIdx.x;
    if (e < NE) {
        int pos = atomicAdd(&cursor[dst[e]], 1);
        srcs[pos] = src[e];
        eids[pos] = e;
    }
}

// ---------------- GEMM: C[M x 128] = A'[M x 128] @ B[128 x 128] ----------------
// Optional per-column input transform (BN+ReLU), optional per-row output scale.
// Output either fp32 (C) or bf16 (Cb) — exactly one non-null.
// k-step 4, b128 LDS reads, v_pk_fma math.
__global__ __launch_bounds__(256) void gemm128(const float* __restrict__ A,
                                               const float* __restrict__ B,
                                               float* __restrict__ C,
                                               unsigned int* __restrict__ Cb,
                                               const float* __restrict__ rowScale,
                                               const float* __restrict__ tA,
                                               const float* __restrict__ tC,
                                               int M) {
    __shared__ float As[64][36];    // [row][k] padded (row pitch 144B, 16B aligned)
    __shared__ float Bs[32][128];   // [k][col]
    int tid = threadIdx.x;
    int tx = tid & 31;              // col group: cols tx*4..tx*4+3
    int ty = tid >> 5;              // row group: rows ty*8..ty*8+7
    int cx = tx * 4;
    int rb = blockIdx.x * 64;

    v4f acc[8];
#pragma unroll
    for (int j = 0; j < 8; j++) acc[j] = (v4f)0.f;

    for (int kb = 0; kb < 128; kb += 32) {
        const float* Bsrc = B + kb * 128;
#pragma unroll
        for (int i = 0; i < 4; i++) {
            int l = 4 * (tid + 256 * i);
            *(float4*)&Bs[l >> 7][l & 127] = *(const float4*)&Bsrc[l];
        }
#pragma unroll
        for (int half = 0; half < 2; half++) {
            int ar = (tid >> 3) + half * 32;
            int ac = (tid & 7) * 4;
            int r = rb + ar;
            float4 av = make_float4(0.f, 0.f, 0.f, 0.f);
            if (r < M) av = *(const float4*)&A[(size_t)r * 128 + kb + ac];
            if (tA) {
                float4 a4 = *(const float4*)&tA[kb + ac];
                float4 c4 = *(const float4*)&tC[kb + ac];
                av.x = fmaxf(av.x * a4.x + c4.x, 0.f);
                av.y = fmaxf(av.y * a4.y + c4.y, 0.f);
                av.z = fmaxf(av.z * a4.z + c4.z, 0.f);
                av.w = fmaxf(av.w * a4.w + c4.w, 0.f);
            }
            *(float4*)&As[ar][ac] = av;
        }
        __syncthreads();
#pragma unroll
        for (int k = 0; k < 32; k += 4) {
            v4f b0 = *(v4f*)&Bs[k][cx];
            v4f b1 = *(v4f*)&Bs[k + 1][cx];
            v4f b2 = *(v4f*)&Bs[k + 2][cx];
            v4f b3 = *(v4f*)&Bs[k + 3][cx];
#pragma unroll
            for (int j = 0; j < 8; j++) {
                v4f a4 = *(v4f*)&As[ty * 8 + j][k];
                acc[j] += b0 * a4.x;
                acc[j] += b1 * a4.y;
                acc[j] += b2 * a4.z;
                acc[j] += b3 * a4.w;
            }
        }
        __syncthreads();
    }
#pragma unroll
    for (int j = 0; j < 8; j++) {
        int r = rb + ty * 8 + j;
        if (r < M) {
            float s = rowScale ? rowScale[r] : 1.f;
            v4f a = acc[j] * s;
            if (Cb) {
                uint2 pk;
                pk.x = packbf2(a.x, a.y);
                pk.y = packbf2(a.z, a.w);
                *(uint2*)&Cb[((size_t)r * 128 + cx) >> 1] = pk;
            } else {
                *(v4f*)&C[(size_t)r * 128 + cx] = a;
            }
        }
    }
}

// ---------------- aggregation: z[n] = dinv[n]*(sum_{e->n} hs[src] + hs[n]) + b ----------------
// hs is bf16-packed (uint = 2 features). Wave per node; uniform scalar index loads;
// 8 independent gathers in flight.
__global__ __launch_bounds__(256) void aggregate_k(const unsigned int* __restrict__ hsb,
                                                   const int* __restrict__ offsets,
                                                   const int* __restrict__ counts,
                                                   const int* __restrict__ srcs,
                                                   const float* __restrict__ dinv,
                                                   const float* __restrict__ bias,
                                                   float* __restrict__ zout) {
    int lane = threadIdx.x & 63;
    int n = __builtin_amdgcn_readfirstlane(blockIdx.x * 4 + (threadIdx.x >> 6));
    if (n >= NN) return;
    int beg = offsets[n];   // uniform -> s_load
    int cnt = counts[n];    // uniform -> s_load
    const int* ss = srcs + beg;
    v2f a0 = {0.f, 0.f}, a1 = {0.f, 0.f}, a2 = {0.f, 0.f}, a3 = {0.f, 0.f};
    v2f a4 = {0.f, 0.f}, a5 = {0.f, 0.f}, a6 = {0.f, 0.f}, a7 = {0.f, 0.f};
    int t = 0;
    for (; t + 8 <= cnt; t += 8) {
        int s0 = ss[t];     // uniform -> batched s_load_dwordx8
        int s1 = ss[t + 1];
        int s2 = ss[t + 2];
        int s3 = ss[t + 3];
        int s4 = ss[t + 4];
        int s5 = ss[t + 5];
        int s6 = ss[t + 6];
        int s7 = ss[t + 7];
        unsigned int u0 = hsb[(size_t)s0 * 64 + lane];
        unsigned int u1 = hsb[(size_t)s1 * 64 + lane];
        unsigned int u2 = hsb[(size_t)s2 * 64 + lane];
        unsigned int u3 = hsb[(size_t)s3 * 64 + lane];
        unsigned int u4 = hsb[(size_t)s4 * 64 + lane];
        unsigned int u5 = hsb[(size_t)s5 * 64 + lane];
        unsigned int u6 = hsb[(size_t)s6 * 64 + lane];
        unsigned int u7 = hsb[(size_t)s7 * 64 + lane];
        a0 += unpackbf2(u0);
        a1 += unpackbf2(u1);
        a2 += unpackbf2(u2);
        a3 += unpackbf2(u3);
        a4 += unpackbf2(u4);
        a5 += unpackbf2(u5);
        a6 += unpackbf2(u6);
        a7 += unpackbf2(u7);
    }
    for (; t < cnt; t++) {
        int s0 = ss[t];
        a0 += unpackbf2(hsb[(size_t)s0 * 64 + lane]);
    }
    v2f self = unpackbf2(hsb[(size_t)n * 64 + lane]);
    float di = dinv[n];
    int f = lane * 2;
    float2 b = *(const float2*)&bias[f];
    v2f sum = ((a0 + a1) + (a2 + a3)) + ((a4 + a5) + (a6 + a7)) + self;
    float2 r;
    r.x = sum.x * di + b.x;
    r.y = sum.y * di + b.y;
    *(float2*)&zout[(size_t)n * 128 + f] = r;
}

// ---------------- BatchNorm stats ----------------
__global__ __launch_bounds__(256) void bnstats_k(const float* __restrict__ z,
                                                 float* __restrict__ sums,
                                                 float* __restrict__ sumsq) {
    __shared__ float ls[128], lq[128];
    int f = threadIdx.x & 127;
    int sub = threadIdx.x >> 7;
    float s = 0.f, q = 0.f;
    for (int r = blockIdx.x * 2 + sub; r < NN; r += gridDim.x * 2) {
        float v = z[(size_t)r * 128 + f];
        s += v;
        q += v * v;
    }
    if (sub) { ls[f] = s; lq[f] = q; }
    __syncthreads();
    if (!sub) {
        atomicAdd(&sums[f], s + ls[f]);
        atomicAdd(&sumsq[f], q + lq[f]);
    }
}

__global__ void bnfinal_k(const float* __restrict__ sums, const float* __restrict__ sumsq,
                          const float* __restrict__ gamma, const float* __restrict__ beta,
                          float* __restrict__ bnA, float* __restrict__ bnC) {
    int f = threadIdx.x;
    if (f < 128) {
        float mean = sums[f] * (1.0f / NN);
        float var = sumsq[f] * (1.0f / NN) - mean * mean;
        float a = gamma[f] * rsqrtf(var + BN_EPS);
        bnA[f] = a;
        bnC[f] = beta[f] - mean * a;
    }
}

// ---------------- edge head (dst-grouped over CSR) ----------------
// out[eo] = relu(P[src] + Q[n] + ea[eo]@We + bm1) . Wm2 + bm2 for each edge eo -> n.
// Wave per node; 4 gathers in flight; ea/indices on scalar pipe; We in VGPRs.
__global__ __launch_bounds__(256) void edgehead_k(const unsigned int* __restrict__ Pb,
                                                  const float* __restrict__ Q,
                                                  const float* __restrict__ ea,
                                                  const int* __restrict__ offsets,
                                                  const int* __restrict__ counts,
                                                  const int* __restrict__ srcs,
                                                  const int* __restrict__ eids,
                                                  const float* __restrict__ We,   // [16][128]
                                                  const float* __restrict__ bm1,
                                                  const float* __restrict__ Wm2,
                                                  const float* __restrict__ bm2,
                                                  float* __restrict__ out) {
    int lane = threadIdx.x & 63;
    int n = __builtin_amdgcn_readfirstlane(blockIdx.x * 4 + (threadIdx.x >> 6));
    if (n >= NN) return;
    int beg = offsets[n];   // uniform
    int cnt = counts[n];    // uniform
    if (cnt == 0) return;
    const int* ss = srcs + beg;
    const int* es = eids + beg;
    int f = lane * 2;
    v2f wreg[16];
#pragma unroll
    for (int k = 0; k < 16; k++) {
        float2 w = *(const float2*)&We[k * 128 + f];
        wreg[k].x = w.x; wreg[k].y = w.y;
    }
    float2 qv = *(const float2*)&Q[(size_t)n * 128 + f];
    float2 bv = *(const float2*)&bm1[f];
    float2 wv = *(const float2*)&Wm2[f];
    float bm2v = bm2[0];
    v2f qb;  // Q + bias folded once per node
    qb.x = qv.x + bv.x;
    qb.y = qv.y + bv.y;

    int t = 0;
    for (; t + 4 <= cnt; t += 4) {
        int s0 = ss[t];       // uniform -> s_load
        int s1 = ss[t + 1];
        int s2 = ss[t + 2];
        int s3 = ss[t + 3];
        int e0 = es[t];
        int e1 = es[t + 1];
        int e2 = es[t + 2];
        int e3 = es[t + 3];
        unsigned int u0 = Pb[(size_t)s0 * 64 + lane];
        unsigned int u1 = Pb[(size_t)s1 * 64 + lane];
        unsigned int u2 = Pb[(size_t)s2 * 64 + lane];
        unsigned int u3 = Pb[(size_t)s3 * 64 + lane];
        const float* ea0 = ea + (size_t)e0 * 16;   // uniform -> s_load_dwordx16
        const float* ea1 = ea + (size_t)e1 * 16;
        const float* ea2 = ea + (size_t)e2 * 16;
        const float* ea3 = ea + (size_t)e3 * 16;
        v2f a0 = qb + unpackbf2(u0);
        v2f a1 = qb + unpackbf2(u1);
        v2f a2 = qb + unpackbf2(u2);
        v2f a3 = qb + unpackbf2(u3);
#pragma unroll
        for (int k = 0; k < 16; k++) {
            a0 += wreg[k] * ea0[k];   // SGPR-operand v_pk_fma
            a1 += wreg[k] * ea1[k];
            a2 += wreg[k] * ea2[k];
            a3 += wreg[k] * ea3[k];
        }
        float v0 = fmaxf(a0.x, 0.f) * wv.x + fmaxf(a0.y, 0.f) * wv.y;
        float v1 = fmaxf(a1.x, 0.f) * wv.x + fmaxf(a1.y, 0.f) * wv.y;
        float v2 = fmaxf(a2.x, 0.f) * wv.x + fmaxf(a2.y, 0.f) * wv.y;
        float v3 = fmaxf(a3.x, 0.f) * wv.x + fmaxf(a3.y, 0.f) * wv.y;
#pragma unroll
        for (int off = 32; off; off >>= 1) {
            v0 += __shfl_xor(v0, off, 64);
            v1 += __shfl_xor(v1, off, 64);
            v2 += __shfl_xor(v2, off, 64);
            v3 += __shfl_xor(v3, off, 64);
        }
        if (lane == 0) {
            out[e0] = v0 + bm2v;
            out[e1] = v1 + bm2v;
            out[e2] = v2 + bm2v;
            out[e3] = v3 + bm2v;
        }
    }
    for (; t < cnt; t++) {
        int s0 = ss[t];
        int e0 = es[t];
        unsigned int u0 = Pb[(size_t)s0 * 64 + lane];
        const float* ea0 = ea + (size_t)e0 * 16;
        v2f a0 = qb + unpackbf2(u0);
#pragma unroll
        for (int k = 0; k < 16; k++) a0 += wreg[k] * ea0[k];
        float v0 = fmaxf(a0.x, 0.f) * wv.x + fmaxf(a0.y, 0.f) * wv.y;
#pragma unroll
        for (int off = 32; off; off >>= 1) v0 += __shfl_xor(v0, off, 64);
        if (lane == 0) out[e0] = v0 + bm2v;
    }
}

// ---------------- launcher ----------------
extern "C" void kernel_launch(void* const* d_in, const int* in_sizes, int n_in,
                              void* d_out, int out_size, void* d_ws, size_t ws_size,
                              hipStream_t stream) {
    const float* x     = (const float*)d_in[0];
    const int*   ei    = (const int*)d_in[1];
    const float* ea    = (const float*)d_in[2];
    const float* W1    = (const float*)d_in[3];
    const float* b1    = (const float*)d_in[4];
    const float* gamma = (const float*)d_in[5];
    const float* beta  = (const float*)d_in[6];
    const float* W2    = (const float*)d_in[7];
    const float* b2    = (const float*)d_in[8];
    const float* Wm1   = (const float*)d_in[9];
    const float* bm1   = (const float*)d_in[10];
    const float* Wm2   = (const float*)d_in[11];
    const float* bm2   = (const float*)d_in[12];
    float* out = (float*)d_out;

    const int* srcI = ei;
    const int* dstI = ei + NE;

    // workspace layout (~46 MB)
    char* w = (char*)d_ws;
    auto alloc = [&](size_t bytes) {
        char* p = w;
        w += (bytes + 255) & ~(size_t)255;
        return p;
    };
    float* dinv    = (float*)alloc(NN * 4);
    int*   counts  = (int*)alloc(NN * 4);
    int*   offsets = (int*)alloc(NN * 4);
    int*   cursor  = (int*)alloc(NN * 4);
    int*   srcs    = (int*)alloc((size_t)NE * 4);
    int*   eids    = (int*)alloc((size_t)NE * 4);
    float* sums    = (float*)alloc(128 * 4);
    float* sumsq   = (float*)alloc(128 * 4);
    float* bnA     = (float*)alloc(128 * 4);
    float* bnC     = (float*)alloc(128 * 4);
    unsigned int* hsb = (unsigned int*)alloc((size_t)NN * 64 * 4);  // bf16 x2 packed
    float* bufZ    = (float*)alloc((size_t)NN * 128 * 4);

    hipMemsetAsync(counts, 0, NN * 4, stream);
    hipMemsetAsync(sums, 0, 128 * 4, stream);
    hipMemsetAsync(sumsq, 0, 128 * 4, stream);

    hist_k<<<(NE + 255) / 256, 256, 0, stream>>>(dstI, counts);
    dinv_k<<<(NN + 255) / 256, 256, 0, stream>>>(counts, dinv);
    scan_k<<<1, 1024, 0, stream>>>(counts, offsets, cursor);
    fill_k<<<(NE + 255) / 256, 256, 0, stream>>>(srcI, dstI, cursor, srcs, eids);

    const int GB = (NN + 63) / 64;
    const int AGG = (NN + 3) / 4;

    // conv1: hs1 = (x@W1)*dinv -> bf16 ; z1 -> bufZ
    gemm128<<<GB, 256, 0, stream>>>(x, W1, nullptr, hsb, dinv, nullptr, nullptr, NN);
    aggregate_k<<<AGG, 256, 0, stream>>>(hsb, offsets, counts, srcs, dinv, b1, bufZ);

    // BN stats (apply fused into conv2 A-staging)
    bnstats_k<<<256, 256, 0, stream>>>(bufZ, sums, sumsq);
    bnfinal_k<<<1, 128, 0, stream>>>(sums, sumsq, gamma, beta, bnA, bnC);

    // conv2: hs2 = (relu(bn(z1))@W2)*dinv -> bf16 ; z2 -> bufZ (z1 dead after GEMM)
    gemm128<<<GB, 256, 0, stream>>>(bufZ, W2, nullptr, hsb, dinv, bnA, bnC, NN);
    aggregate_k<<<AGG, 256, 0, stream>>>(hsb, offsets, counts, srcs, dinv, b2, bufZ);

    // edge head precompute: P = z2@Ws -> bf16 (hsb reused); Q = z2@Wd -> bufZ in-place
    gemm128<<<GB, 256, 0, stream>>>(bufZ, Wm1, nullptr, hsb, nullptr, nullptr, nullptr, NN);
    gemm128<<<GB, 256, 0, stream>>>(bufZ, Wm1 + 128 * 128, bufZ, nullptr, nullptr, nullptr, nullptr, NN);

    edgehead_k<<<AGG, 256, 0, stream>>>(hsb, bufZ, ea, offsets, counts, srcs, eids,
                                        Wm1 + 256 * 128, bm1, Wm2, bm2, out);
}